// Round 2
// baseline (72.105 us; speedup 1.0000x reference)
//
#include <hip/hip_runtime.h>

#define NBITS 13
#define DMODEL 1024

// out[p, d] = sum over set bits b of x[p] of emb[b, d]
// One block iteration handles one position: 256 threads x float4 = 1024 cols.
// emb fragment (13 x float4 per thread) is hoisted into registers once.
__global__ __launch_bounds__(256) void bpe_kernel(const int* __restrict__ x,
                                                  const float* __restrict__ emb,
                                                  float* __restrict__ out,
                                                  int npos) {
    const int t = threadIdx.x;  // 0..255, owns columns 4t..4t+3

    // Hoist this thread's slice of emb into registers: 13 x float4 = 52 VGPRs.
    float4 frag[NBITS];
#pragma unroll
    for (int b = 0; b < NBITS; ++b) {
        frag[b] = *reinterpret_cast<const float4*>(emb + b * DMODEL + t * 4);
    }

    for (int p = blockIdx.x; p < npos; p += gridDim.x) {
        const int xv = x[p];  // block-uniform -> scalar load + branch
        float4 acc = make_float4(0.f, 0.f, 0.f, 0.f);
#pragma unroll
        for (int b = 0; b < NBITS; ++b) {
            if (xv & (1 << b)) {
                acc.x += frag[b].x;
                acc.y += frag[b].y;
                acc.z += frag[b].z;
                acc.w += frag[b].w;
            }
        }
        *reinterpret_cast<float4*>(out + (size_t)p * DMODEL + (size_t)t * 4) = acc;
    }
}

extern "C" void kernel_launch(void* const* d_in, const int* in_sizes, int n_in,
                              void* d_out, int out_size, void* d_ws, size_t ws_size,
                              hipStream_t stream) {
    const int* x = (const int*)d_in[0];        // (4, 8192) int32, flat 32768
    const float* emb = (const float*)d_in[1];  // (13, 1024) float32
    float* out = (float*)d_out;                // (4, 8192, 1024) float32

    const int npos = in_sizes[0];  // 32768

    // 2048 blocks = 8 blocks/CU on 256 CUs; each block grid-strides 16 positions.
    int grid = npos < 2048 ? npos : 2048;
    bpe_kernel<<<grid, 256, 0, stream>>>(x, emb, out, npos);
}

// Round 3
// 28.033 us; speedup vs baseline: 2.5721x; 2.5721x over previous
//
#include <hip/hip_runtime.h>

#define NBITS 13
#define DMODEL 1024

// out[p, d] = sum over set bits b of x[p] of emb[b, d]
// 256 threads x float4 = 1024 cols per position. emb fragment hoisted to
// registers once per block. 4 positions per loop iteration, branchless
// (scalar-select 1.0/0.0 multiplier + v_fmac), giving 4 independent store
// streams and a pipelineable single-basic-block loop body.
__global__ __launch_bounds__(256) void bpe_kernel(const int* __restrict__ x,
                                                  const float* __restrict__ emb,
                                                  float* __restrict__ out,
                                                  int npos) {
    const int t = threadIdx.x;  // owns columns 4t..4t+3

    // 13 x float4 = 52 VGPRs of emb slice, loaded once per block.
    float4 frag[NBITS];
#pragma unroll
    for (int b = 0; b < NBITS; ++b) {
        frag[b] = *reinterpret_cast<const float4*>(emb + b * DMODEL + t * 4);
    }

    const int stride = gridDim.x * 4;
    int p0 = blockIdx.x * 4;
    for (; p0 + 3 < npos; p0 += stride) {
        // 4 block-uniform x values in one scalar dwordx4 load.
        const int4 xv = *reinterpret_cast<const int4*>(x + p0);

        float4 a0 = make_float4(0.f, 0.f, 0.f, 0.f);
        float4 a1 = a0, a2 = a0, a3 = a0;
#pragma unroll
        for (int b = 0; b < NBITS; ++b) {
            // 1.0f / 0.0f via bit select: uniform -> s_cselect, no VALU cvt.
            const float m0 = __int_as_float(((xv.x >> b) & 1) ? 0x3f800000 : 0);
            const float m1 = __int_as_float(((xv.y >> b) & 1) ? 0x3f800000 : 0);
            const float m2 = __int_as_float(((xv.z >> b) & 1) ? 0x3f800000 : 0);
            const float m3 = __int_as_float(((xv.w >> b) & 1) ? 0x3f800000 : 0);
            a0.x = fmaf(m0, frag[b].x, a0.x);
            a0.y = fmaf(m0, frag[b].y, a0.y);
            a0.z = fmaf(m0, frag[b].z, a0.z);
            a0.w = fmaf(m0, frag[b].w, a0.w);
            a1.x = fmaf(m1, frag[b].x, a1.x);
            a1.y = fmaf(m1, frag[b].y, a1.y);
            a1.z = fmaf(m1, frag[b].z, a1.z);
            a1.w = fmaf(m1, frag[b].w, a1.w);
            a2.x = fmaf(m2, frag[b].x, a2.x);
            a2.y = fmaf(m2, frag[b].y, a2.y);
            a2.z = fmaf(m2, frag[b].z, a2.z);
            a2.w = fmaf(m2, frag[b].w, a2.w);
            a3.x = fmaf(m3, frag[b].x, a3.x);
            a3.y = fmaf(m3, frag[b].y, a3.y);
            a3.z = fmaf(m3, frag[b].z, a3.z);
            a3.w = fmaf(m3, frag[b].w, a3.w);
        }

        float* o = out + (size_t)p0 * DMODEL + (size_t)(t * 4);
        *reinterpret_cast<float4*>(o) = a0;
        *reinterpret_cast<float4*>(o + DMODEL) = a1;
        *reinterpret_cast<float4*>(o + 2 * DMODEL) = a2;
        *reinterpret_cast<float4*>(o + 3 * DMODEL) = a3;
    }

    // Tail for npos % 4 != 0 (not hit for npos=32768, kept for safety).
    for (int p = (npos & ~3) + blockIdx.x; p < npos; p += gridDim.x) {
        const int xv = x[p];
        float4 acc = make_float4(0.f, 0.f, 0.f, 0.f);
#pragma unroll
        for (int b = 0; b < NBITS; ++b) {
            const float m = __int_as_float(((xv >> b) & 1) ? 0x3f800000 : 0);
            acc.x = fmaf(m, frag[b].x, acc.x);
            acc.y = fmaf(m, frag[b].y, acc.y);
            acc.z = fmaf(m, frag[b].z, acc.z);
            acc.w = fmaf(m, frag[b].w, acc.w);
        }
        *reinterpret_cast<float4*>(out + (size_t)p * DMODEL + (size_t)(t * 4)) = acc;
    }
}

extern "C" void kernel_launch(void* const* d_in, const int* in_sizes, int n_in,
                              void* d_out, int out_size, void* d_ws, size_t ws_size,
                              hipStream_t stream) {
    const int* x = (const int*)d_in[0];        // (4, 8192) int32, flat 32768
    const float* emb = (const float*)d_in[1];  // (13, 1024) float32
    float* out = (float*)d_out;                // (4, 8192, 1024) float32

    const int npos = in_sizes[0];  // 32768

    // 2048 blocks = 8 blocks/CU; each block handles 4 groups of 4 positions.
    int ngroups = (npos + 3) / 4;
    int grid = ngroups < 2048 ? ngroups : 2048;
    bpe_kernel<<<grid, 256, 0, stream>>>(x, emb, out, npos);
}

// Round 4
// 26.599 us; speedup vs baseline: 2.7108x; 1.0539x over previous
//
#include <hip/hip_runtime.h>

#define NBITS 13
#define DMODEL 1024
#define PPB 16  // positions per block: 16 x 4 KB = 64 KB contiguous output/block

// out[p, d] = sum over set bits b of x[p] of emb[b, d]
// One block = 16 consecutive positions, fully unrolled. Each position computes
// into a fresh accumulator and stores immediately -> no vmcnt register-reuse
// stalls; 16 independent global_store_dwordx4 streams per wave.
__global__ __launch_bounds__(256) void bpe_kernel(const int* __restrict__ x,
                                                  const float* __restrict__ emb,
                                                  float* __restrict__ out,
                                                  int npos) {
    const int t = threadIdx.x;  // owns columns 4t..4t+3

    // 13 x float4 = 52 VGPRs of emb slice, loaded once per block (L2-hit).
    float4 frag[NBITS];
#pragma unroll
    for (int b = 0; b < NBITS; ++b) {
        frag[b] = *reinterpret_cast<const float4*>(emb + b * DMODEL + t * 4);
    }

    const int base = blockIdx.x * PPB;

    if (base + PPB <= npos) {
        // All 16 x values up front: wave-uniform addresses -> scalar dwordx4 loads.
        int xv[PPB];
#pragma unroll
        for (int i = 0; i < PPB; i += 4) {
            const int4 v = *reinterpret_cast<const int4*>(x + base + i);
            xv[i + 0] = v.x;
            xv[i + 1] = v.y;
            xv[i + 2] = v.z;
            xv[i + 3] = v.w;
        }

        float* o = out + (size_t)base * DMODEL + (size_t)(t * 4);
#pragma unroll
        for (int i = 0; i < PPB; ++i) {
            const int v = xv[i];
            float4 acc = make_float4(0.f, 0.f, 0.f, 0.f);
#pragma unroll
            for (int b = 0; b < NBITS; ++b) {
                // 1.0f/0.0f multiplier via uniform bit select (s_cselect).
                const float m = __int_as_float(((v >> b) & 1) ? 0x3f800000 : 0);
                acc.x = fmaf(m, frag[b].x, acc.x);
                acc.y = fmaf(m, frag[b].y, acc.y);
                acc.z = fmaf(m, frag[b].z, acc.z);
                acc.w = fmaf(m, frag[b].w, acc.w);
            }
            // Fresh registers every position: store never blocks later compute.
            *reinterpret_cast<float4*>(o + (size_t)i * DMODEL) = acc;
        }
    } else {
        // Tail (npos % 16 != 0) — not hit for npos=32768.
        for (int p = base; p < npos; ++p) {
            const int v = x[p];
            float4 acc = make_float4(0.f, 0.f, 0.f, 0.f);
#pragma unroll
            for (int b = 0; b < NBITS; ++b) {
                const float m = __int_as_float(((v >> b) & 1) ? 0x3f800000 : 0);
                acc.x = fmaf(m, frag[b].x, acc.x);
                acc.y = fmaf(m, frag[b].y, acc.y);
                acc.z = fmaf(m, frag[b].z, acc.z);
                acc.w = fmaf(m, frag[b].w, acc.w);
            }
            *reinterpret_cast<float4*>(out + (size_t)p * DMODEL + (size_t)(t * 4)) = acc;
        }
    }
}

extern "C" void kernel_launch(void* const* d_in, const int* in_sizes, int n_in,
                              void* d_out, int out_size, void* d_ws, size_t ws_size,
                              hipStream_t stream) {
    const int* x = (const int*)d_in[0];        // (4, 8192) int32, flat 32768
    const float* emb = (const float*)d_in[1];  // (13, 1024) float32
    float* out = (float*)d_out;                // (4, 8192, 1024) float32

    const int npos = in_sizes[0];  // 32768

    const int grid = (npos + PPB - 1) / PPB;   // 2048 blocks for npos=32768
    bpe_kernel<<<grid, 256, 0, stream>>>(x, emb, out, npos);
}